// Round 1
// baseline (309.003 us; speedup 1.0000x reference)
//
#include <hip/hip_runtime.h>

#define SEQ 2048
#define NHEADS 16

typedef short short8 __attribute__((ext_vector_type(8)));   // 8 bf16 (4 VGPRs)
typedef float floatx4 __attribute__((ext_vector_type(4)));  // 4 fp32 acc

static __device__ __forceinline__ unsigned short f2bf(float f) {
    unsigned int u = __builtin_bit_cast(unsigned int, f);
    u = (u + 0x7fffu + ((u >> 16) & 1u)) >> 16;   // RNE
    return (unsigned short)u;
}

// ---------------- fp32 -> bf16 convert (optionally scaled) ----------------
__global__ void cvt_kernel(const float4* __restrict__ src, ushort4* __restrict__ dst,
                           int n4, float scale) {
    int i = blockIdx.x * blockDim.x + threadIdx.x;
    if (i < n4) {
        float4 v = src[i];
        ushort4 o;
        o.x = f2bf(v.x * scale); o.y = f2bf(v.y * scale);
        o.z = f2bf(v.z * scale); o.w = f2bf(v.w * scale);
        dst[i] = o;
    }
}

// ---------------- W [K][N] fp32  ->  Wt [N][K] bf16 ----------------
__global__ void transpose_w(const float* __restrict__ in, unsigned short* __restrict__ out,
                            int K, int N) {
    __shared__ float tile[32][33];
    int n0 = blockIdx.x * 32, k0 = blockIdx.y * 32;
    int tx = threadIdx.x, ty = threadIdx.y;
#pragma unroll
    for (int i = 0; i < 4; i++)
        tile[ty + i * 8][tx] = in[(size_t)(k0 + ty + i * 8) * N + n0 + tx];
    __syncthreads();
#pragma unroll
    for (int i = 0; i < 4; i++)
        out[(size_t)(n0 + ty + i * 8) * K + k0 + tx] = f2bf(tile[tx][ty + i * 8]);
}

// ---------------- bf16 GEMM: C[4096 x NCOLS] = A[4096x1024] * Bt^T ----------------
// MODE 0: write q_ws[bh][n][d] bf16        (NCOLS=1024)
// MODE 1: write k_ws[bh][n][d], vt_ws[bh][d][n] bf16  (NCOLS=2048)
// MODE 2: write out fp32 + bias            (NCOLS=1024)
template <int MODE>
__global__ __launch_bounds__(256, 2)
void gemm_bf16(const unsigned short* __restrict__ A,
               const unsigned short* __restrict__ Bt,
               unsigned short* __restrict__ o_a,
               unsigned short* __restrict__ o_v,
               float* __restrict__ o_f,
               const float* __restrict__ bias) {
    __shared__ unsigned short sA[128][72];  // +8 pad: 2-way banks (free)
    __shared__ unsigned short sB[128][72];
    int tid = threadIdx.x;
    int wave = tid >> 6, lane = tid & 63;
    int l15 = lane & 15, quad = lane >> 4;
    int R0 = blockIdx.y * 128, C0 = blockIdx.x * 128;
    int wr = (wave >> 1) * 64, wc = (wave & 1) * 64;

    floatx4 acc[4][4];
#pragma unroll
    for (int i = 0; i < 4; i++)
#pragma unroll
        for (int j = 0; j < 4; j++) acc[i][j] = (floatx4){0.f, 0.f, 0.f, 0.f};

    for (int kt = 0; kt < 16; kt++) {
        __syncthreads();
#pragma unroll
        for (int i = 0; i < 4; i++) {
            int ch = tid + i * 256;           // 1024 chunks of 8 bf16
            int row = ch >> 3, kc = (ch & 7) * 8;
            *(int4*)&sA[row][kc] = *(const int4*)&A[(size_t)(R0 + row) * 1024 + kt * 64 + kc];
            *(int4*)&sB[row][kc] = *(const int4*)&Bt[(size_t)(C0 + row) * 1024 + kt * 64 + kc];
        }
        __syncthreads();
#pragma unroll
        for (int ks = 0; ks < 2; ks++) {
            short8 af[4], bf[4];
#pragma unroll
            for (int mt = 0; mt < 4; mt++)
                af[mt] = *(const short8*)&sA[wr + mt * 16 + l15][ks * 32 + quad * 8];
#pragma unroll
            for (int nt = 0; nt < 4; nt++)
                bf[nt] = *(const short8*)&sB[wc + nt * 16 + l15][ks * 32 + quad * 8];
#pragma unroll
            for (int mt = 0; mt < 4; mt++)
#pragma unroll
                for (int nt = 0; nt < 4; nt++)
                    acc[mt][nt] = __builtin_amdgcn_mfma_f32_16x16x32_bf16(af[mt], bf[nt], acc[mt][nt], 0, 0, 0);
        }
    }

#pragma unroll
    for (int mt = 0; mt < 4; mt++) {
#pragma unroll
        for (int r = 0; r < 4; r++) {
            int row = R0 + wr + mt * 16 + quad * 4 + r;   // C/D: row=quad*4+reg
            int b = row >> 11, n = row & 2047;
#pragma unroll
            for (int nt = 0; nt < 4; nt++) {
                int col = C0 + wc + nt * 16 + l15;        // C/D: col=lane&15
                float v = acc[mt][nt][r];
                if (MODE == 0) {
                    int h = col >> 6, d = col & 63;
                    o_a[((size_t)((b * 16 + h) * 2048 + n)) * 64 + d] = f2bf(v);
                } else if (MODE == 1) {
                    int which = col >> 10, cc = col & 1023;
                    int h = cc >> 6, d = cc & 63;
                    if (which == 0)
                        o_a[((size_t)((b * 16 + h) * 2048 + n)) * 64 + d] = f2bf(v);
                    else
                        o_v[((size_t)((b * 16 + h) * 64 + d)) * 2048 + n] = f2bf(v);
                } else {
                    o_f[(size_t)row * 1024 + col] = v + bias[col];
                }
            }
        }
    }
}

// ---------------- flash attention ----------------
// grid (16 q-tiles, 32 bh), 256 threads = 4 waves x 32 q-rows; 64-key tiles.
__global__ __launch_bounds__(256, 2)
void attn_kernel(const unsigned short* __restrict__ Q,   // [32][2048][64]
                 const unsigned short* __restrict__ K,   // [32][2048][64]
                 const unsigned short* __restrict__ Vt,  // [32][64][2048]
                 unsigned short* __restrict__ Aout) {    // [4096][1024] bf16
    __shared__ unsigned short sQ[128][72];
    __shared__ unsigned short sK[64][72];
    __shared__ unsigned short sV[64][72];        // sV[d][key]
    __shared__ unsigned short sP[4][32][72];     // per-wave P round-trip

    int tid = threadIdx.x, wave = tid >> 6, lane = tid & 63;
    int l15 = lane & 15, quad = lane >> 4;
    int bh = blockIdx.y, b = bh >> 4, h = bh & 15;
    int qr0 = blockIdx.x * 128;

    const unsigned short* Qp = Q + (size_t)bh * SEQ * 64;
    const unsigned short* Kp = K + (size_t)bh * SEQ * 64;
    const unsigned short* Vp = Vt + (size_t)bh * 64 * SEQ;

#pragma unroll
    for (int i = 0; i < 4; i++) {
        int ch = tid + i * 256;
        int row = ch >> 3, kc = (ch & 7) * 8;
        *(int4*)&sQ[row][kc] = *(const int4*)&Qp[(size_t)(qr0 + row) * 64 + kc];
    }
    __syncthreads();

    short8 qf[2][2];   // Q A-frags, loaded once
#pragma unroll
    for (int mt = 0; mt < 2; mt++)
#pragma unroll
        for (int kh = 0; kh < 2; kh++)
            qf[mt][kh] = *(const short8*)&sQ[wave * 32 + mt * 16 + l15][kh * 32 + quad * 8];

    floatx4 of[2][4];
#pragma unroll
    for (int i = 0; i < 2; i++)
#pragma unroll
        for (int j = 0; j < 4; j++) of[i][j] = (floatx4){0.f, 0.f, 0.f, 0.f};
    float m_run[2][4], l_run[2][4];
#pragma unroll
    for (int i = 0; i < 2; i++)
#pragma unroll
        for (int r = 0; r < 4; r++) { m_run[i][r] = -1e30f; l_run[i][r] = 0.f; }

    for (int kt = 0; kt < 32; kt++) {
        int k0 = kt * 64;
        __syncthreads();                       // protect sK/sV vs prev iter reads
#pragma unroll
        for (int i = 0; i < 2; i++) {
            int ch = tid + i * 256;            // 512 chunks each
            int row = ch >> 3, kc = (ch & 7) * 8;
            *(int4*)&sK[row][kc] = *(const int4*)&Kp[(size_t)(k0 + row) * 64 + kc];
            *(int4*)&sV[row][kc] = *(const int4*)&Vp[(size_t)row * SEQ + k0 + kc];
        }
        __syncthreads();

        // S = Q*K^T (scale pre-folded into x_t)
        floatx4 sacc[2][4];
        floatx4 zero = (floatx4){0.f, 0.f, 0.f, 0.f};
#pragma unroll
        for (int f = 0; f < 4; f++) {
            short8 kf0 = *(const short8*)&sK[f * 16 + l15][quad * 8];
            short8 kf1 = *(const short8*)&sK[f * 16 + l15][32 + quad * 8];
#pragma unroll
            for (int mt = 0; mt < 2; mt++) {
                floatx4 t = __builtin_amdgcn_mfma_f32_16x16x32_bf16(qf[mt][0], kf0, zero, 0, 0, 0);
                sacc[mt][f] = __builtin_amdgcn_mfma_f32_16x16x32_bf16(qf[mt][1], kf1, t, 0, 0, 0);
            }
        }

        // online softmax (rows distributed: row=quad*4+r, cols=lane&15 per f-tile)
#pragma unroll
        for (int mt = 0; mt < 2; mt++) {
#pragma unroll
            for (int r = 0; r < 4; r++) {
                float v = sacc[mt][0][r];
                v = fmaxf(v, sacc[mt][1][r]);
                v = fmaxf(v, sacc[mt][2][r]);
                v = fmaxf(v, sacc[mt][3][r]);
#pragma unroll
                for (int off = 1; off < 16; off <<= 1)
                    v = fmaxf(v, __shfl_xor(v, off, 64));
                float newm = fmaxf(m_run[mt][r], v);
                float alpha = __expf(m_run[mt][r] - newm);
                m_run[mt][r] = newm;
                float s = 0.f;
#pragma unroll
                for (int f = 0; f < 4; f++) {
                    float p = __expf(sacc[mt][f][r] - newm);
                    sacc[mt][f][r] = p;
                    s += p;
                }
#pragma unroll
                for (int off = 1; off < 16; off <<= 1)
                    s += __shfl_xor(s, off, 64);
                l_run[mt][r] = l_run[mt][r] * alpha + s;
#pragma unroll
                for (int df = 0; df < 4; df++)
                    of[mt][df][r] *= alpha;
#pragma unroll
                for (int f = 0; f < 4; f++)
                    sP[wave][mt * 16 + quad * 4 + r][f * 16 + l15] = f2bf(sacc[mt][f][r]);
            }
        }
        __syncthreads();   // P write -> A-layout read (conservative round 1)

        // O += P * V
#pragma unroll
        for (int kk = 0; kk < 2; kk++) {
            short8 pf[2];
#pragma unroll
            for (int mt = 0; mt < 2; mt++)
                pf[mt] = *(const short8*)&sP[wave][mt * 16 + l15][kk * 32 + quad * 8];
#pragma unroll
            for (int df = 0; df < 4; df++) {
                short8 vf = *(const short8*)&sV[df * 16 + l15][kk * 32 + quad * 8];
#pragma unroll
                for (int mt = 0; mt < 2; mt++)
                    of[mt][df] = __builtin_amdgcn_mfma_f32_16x16x32_bf16(pf[mt], vf, of[mt][df], 0, 0, 0);
            }
        }
    }

    // epilogue: a[b][n][h*64+d] bf16
#pragma unroll
    for (int mt = 0; mt < 2; mt++) {
#pragma unroll
        for (int r = 0; r < 4; r++) {
            int row = qr0 + wave * 32 + mt * 16 + quad * 4 + r;
            float inv = 1.f / l_run[mt][r];
#pragma unroll
            for (int df = 0; df < 4; df++) {
                int d = df * 16 + l15;
                Aout[(size_t)(b * SEQ + row) * 1024 + h * 64 + d] = f2bf(of[mt][df][r] * inv);
            }
        }
    }
}

extern "C" void kernel_launch(void* const* d_in, const int* in_sizes, int n_in,
                              void* d_out, int out_size, void* d_ws, size_t ws_size,
                              hipStream_t stream) {
    const float* x_t  = (const float*)d_in[0];
    const float* x_s  = (const float*)d_in[1];
    const float* W_q  = (const float*)d_in[2];
    const float* W_kv = (const float*)d_in[3];
    const float* W_f  = (const float*)d_in[4];
    const float* b_f  = (const float*)d_in[5];
    float* out = (float*)d_out;

    char* ws = (char*)d_ws;
    const size_t MB = 1u << 20;
    unsigned short* xt_bf = (unsigned short*)(ws);            // 8 MB
    unsigned short* xs_bf = (unsigned short*)(ws + 8 * MB);   // 8 MB
    unsigned short* wq_t  = (unsigned short*)(ws + 16 * MB);  // 2 MB
    unsigned short* wkv_t = (unsigned short*)(ws + 18 * MB);  // 4 MB
    unsigned short* wf_t  = (unsigned short*)(ws + 22 * MB);  // 2 MB
    unsigned short* q_ws  = (unsigned short*)(ws + 24 * MB);  // 8 MB
    unsigned short* k_ws  = (unsigned short*)(ws + 32 * MB);  // 8 MB
    unsigned short* vt_ws = (unsigned short*)(ws + 40 * MB);  // 8 MB
    unsigned short* a_ws  = (unsigned short*)(ws + 48 * MB);  // 8 MB (total 56 MB)

    // SCALE = 1/8 folded into x_t (exact exponent shift in bf16)
    cvt_kernel<<<4096, 256, 0, stream>>>((const float4*)x_t, (ushort4*)xt_bf, 1048576, 0.125f);
    cvt_kernel<<<4096, 256, 0, stream>>>((const float4*)x_s, (ushort4*)xs_bf, 1048576, 1.0f);
    transpose_w<<<dim3(32, 32), dim3(32, 8), 0, stream>>>(W_q, wq_t, 1024, 1024);
    transpose_w<<<dim3(64, 32), dim3(32, 8), 0, stream>>>(W_kv, wkv_t, 1024, 2048);
    transpose_w<<<dim3(32, 32), dim3(32, 8), 0, stream>>>(W_f, wf_t, 1024, 1024);

    gemm_bf16<0><<<dim3(8, 32), 256, 0, stream>>>(xt_bf, wq_t, q_ws, nullptr, nullptr, nullptr);
    gemm_bf16<1><<<dim3(16, 32), 256, 0, stream>>>(xs_bf, wkv_t, k_ws, vt_ws, nullptr, nullptr);
    attn_kernel<<<dim3(16, 32), 256, 0, stream>>>(q_ws, k_ws, vt_ws, a_ws);
    gemm_bf16<2><<<dim3(8, 32), 256, 0, stream>>>(a_ws, wf_t, nullptr, nullptr, out, b_f);
}